// Round 6
// baseline (1402.329 us; speedup 1.0000x reference)
//
#include <hip/hip_runtime.h>
#include <hip/hip_bf16.h>
#include <math.h>

#define NN 100000
#define EE 1600000
#define DD 128
#define HH 8
#define CC 16
#define EDD 16
#define NBLK 98  // ceil(NN/1024)

typedef unsigned short u16;
typedef unsigned int u32;
typedef __attribute__((ext_vector_type(8))) short short8;
typedef __attribute__((ext_vector_type(4))) float f32x4;

__device__ __forceinline__ u16 f2bf(float f) {
  u32 u = __float_as_uint(f);
  u32 r = u + 0x7fff + ((u >> 16) & 1);
  return (u16)(r >> 16);
}

// ---------------- CSR build ----------------

__global__ void k_hist(const int* __restrict__ ei, int* __restrict__ cnt) {
  int stride = gridDim.x * blockDim.x;
  for (int e = blockIdx.x * blockDim.x + threadIdx.x; e < EE; e += stride)
    atomicAdd(&cnt[ei[EE + e]], 1);
}

__global__ __launch_bounds__(1024) void k_scan_a(const int* __restrict__ cnt,
                                                 int* __restrict__ loc,
                                                 int* __restrict__ bsum) {
  __shared__ int wpart[16];
  int t = threadIdx.x, lane = t & 63, w = t >> 6;
  int i = blockIdx.x * 1024 + t;
  int v = (i < NN) ? cnt[i] : 0;
  int x = v;
#pragma unroll
  for (int d = 1; d < 64; d <<= 1) {
    int y = __shfl_up(x, d, 64);
    if (lane >= d) x += y;
  }
  if (lane == 63) wpart[w] = x;
  __syncthreads();
  if (w == 0) {
    int p = (lane < 16) ? wpart[lane] : 0;
#pragma unroll
    for (int d = 1; d < 16; d <<= 1) {
      int y = __shfl_up(p, d, 64);
      if (lane >= d) p += y;
    }
    if (lane < 16) wpart[lane] = p;
  }
  __syncthreads();
  int excl = ((w > 0) ? wpart[w - 1] : 0) + (x - v);
  if (i < NN) loc[i] = excl;
  if (t == 0) bsum[blockIdx.x] = wpart[15];
}

__global__ void k_scan_b(int* __restrict__ bsum, int* __restrict__ off) {
  if (blockIdx.x == 0 && threadIdx.x == 0) {
    int run = 0;
    for (int b = 0; b < NBLK; b++) { int s = bsum[b]; bsum[b] = run; run += s; }
    off[NN] = run;
  }
}

__global__ __launch_bounds__(1024) void k_scan_c(const int* __restrict__ loc,
                                                 const int* __restrict__ bsum,
                                                 int* __restrict__ off,
                                                 int* __restrict__ cur) {
  int i = blockIdx.x * 1024 + threadIdx.x;
  if (i < NN) {
    int v = loc[i] + bsum[i >> 10];
    off[i] = v;
    cur[i] = v;
  }
}

__global__ void k_scatter(const int* __restrict__ ei, int* __restrict__ cur,
                          int* __restrict__ perm) {
  int stride = gridDim.x * blockDim.x;
  for (int e = blockIdx.x * blockDim.x + threadIdx.x; e < EE; e += stride) {
    int d = ei[EE + e];
    int p = atomicAdd(&cur[d], 1);
    perm[p] = e;
  }
}

// ---------------- prep: bf16-transposed weights + WA ----------------

__global__ void k_prep(const float* __restrict__ linW, const float* __restrict__ W1,
                       const float* __restrict__ W2, const float* __restrict__ wle,
                       const float* __restrict__ attE, u16* __restrict__ Btg,
                       float* __restrict__ WAg) {
  int tid = blockIdx.x * 256 + threadIdx.x;
  if (tid < 6144) {
    int m = tid >> 11;
    int cid = tid & 2047;
    const float* W = (m == 0) ? linW : (m == 1) ? W1 : W2;
    int n = cid >> 4, kc = cid & 15;
    union { u16 us[8]; uint4 q4; } P;
#pragma unroll
    for (int j = 0; j < 8; j++) P.us[j] = f2bf(W[(kc * 8 + j) * 128 + n]);
    ((uint4*)(Btg + (size_t)m * 16384))[cid] = P.q4;
  } else if (tid < 6272) {
    int i = tid - 6144;
    int k = i >> 3, h = i & 7;
    float s = 0.f;
#pragma unroll
    for (int c = 0; c < 16; c++) s += wle[k * 128 + h * 16 + c] * attE[h * 16 + c];
    WAg[k * 8 + h] = s;
  }
}

// ---------------- bf16 MFMA GEMM: [N x 128] @ [128 x 128] ----------------
// EPI: 0 = f32 store, 1 = bias+gelu, 2 = bias+residual+LN2, 3 = bf16 store

template <int EPI>
__global__ __launch_bounds__(256) void k_gemm(
    const float* __restrict__ A, const u16* __restrict__ Bt,
    const float* __restrict__ bias, const float* __restrict__ resid,
    const float* __restrict__ lng, const float* __restrict__ lnb,
    float* __restrict__ Cout) {
  __shared__ u16 As[64 * 136];
  __shared__ u16 Bs[128 * 136];
  int t = threadIdx.x;
  int row0 = blockIdx.x * 64;
#pragma unroll
  for (int i = 0; i < 8; i++) {
    int cid = t + 256 * i;
    int n = cid >> 4, kc = cid & 15;
    uint4 v = ((const uint4*)Bt)[cid];
    *((uint4*)(&Bs[n * 136 + kc * 8])) = v;
  }
  {
    int r = t >> 2, q = t & 3;
    const float* Ar = A + (size_t)(row0 + r) * 128 + q * 32;
    bool ok = (row0 + r) < NN;
#pragma unroll
    for (int j = 0; j < 4; j++) {
      float4 u = ok ? ((const float4*)Ar)[2 * j] : make_float4(0.f, 0.f, 0.f, 0.f);
      float4 v = ok ? ((const float4*)Ar)[2 * j + 1] : make_float4(0.f, 0.f, 0.f, 0.f);
      union { u16 us[8]; uint4 q4; } P;
      P.us[0] = f2bf(u.x); P.us[1] = f2bf(u.y); P.us[2] = f2bf(u.z); P.us[3] = f2bf(u.w);
      P.us[4] = f2bf(v.x); P.us[5] = f2bf(v.y); P.us[6] = f2bf(v.z); P.us[7] = f2bf(v.w);
      *((uint4*)(&As[r * 136 + (q * 4 + j) * 8])) = P.q4;
    }
  }
  __syncthreads();
  int w = t >> 6, lane = t & 63, lo = lane & 15, hi = lane >> 4;
  f32x4 acc[8];
  f32x4 zero = {0.f, 0.f, 0.f, 0.f};
#pragma unroll
  for (int i = 0; i < 8; i++) acc[i] = zero;
  const u16* ApL = &As[(w * 16 + lo) * 136];
  const u16* BpL = &Bs[lo * 136];
#pragma unroll
  for (int ks = 0; ks < 4; ks++) {
    short8 af = *((const short8*)(ApL + ks * 32 + hi * 8));
#pragma unroll
    for (int tt = 0; tt < 8; tt++) {
      short8 bf = *((const short8*)(BpL + tt * 16 * 136 + ks * 32 + hi * 8));
      acc[tt] = __builtin_amdgcn_mfma_f32_16x16x32_bf16(af, bf, acc[tt], 0, 0, 0);
    }
  }
  if (EPI == 0) {
#pragma unroll
    for (int j = 0; j < 4; j++) {
      int row = row0 + w * 16 + hi * 4 + j;
      if (row < NN) {
#pragma unroll
        for (int tt = 0; tt < 8; tt++)
          Cout[(size_t)row * 128 + tt * 16 + lo] = acc[tt][j];
      }
    }
  } else if (EPI == 3) {
    u16* Cb = (u16*)Cout;
#pragma unroll
    for (int j = 0; j < 4; j++) {
      int row = row0 + w * 16 + hi * 4 + j;
      if (row < NN) {
#pragma unroll
        for (int tt = 0; tt < 8; tt++)
          Cb[(size_t)row * 128 + tt * 16 + lo] = f2bf(acc[tt][j]);
      }
    }
  } else if (EPI == 1) {
#pragma unroll
    for (int j = 0; j < 4; j++) {
      int row = row0 + w * 16 + hi * 4 + j;
      if (row < NN) {
#pragma unroll
        for (int tt = 0; tt < 8; tt++) {
          int col = tt * 16 + lo;
          float z = acc[tt][j] + bias[col];
          float g = 0.5f * z * (1.f + erff(z * 0.70710678118654752f));
          Cout[(size_t)row * 128 + col] = g;
        }
      }
    }
  } else {
#pragma unroll
    for (int j = 0; j < 4; j++) {
      int row = row0 + w * 16 + hi * 4 + j;
      bool rok = row < NN;
      float v[8];
      float sum = 0.f;
#pragma unroll
      for (int tt = 0; tt < 8; tt++) {
        int col = tt * 16 + lo;
        float hv = rok ? resid[(size_t)row * 128 + col] : 0.f;
        v[tt] = hv + acc[tt][j] + bias[col];
        sum += v[tt];
      }
      sum += __shfl_xor(sum, 1, 64); sum += __shfl_xor(sum, 2, 64);
      sum += __shfl_xor(sum, 4, 64); sum += __shfl_xor(sum, 8, 64);
      float mu = sum * (1.f / 128.f);
      float var = 0.f;
#pragma unroll
      for (int tt = 0; tt < 8; tt++) { v[tt] -= mu; var += v[tt] * v[tt]; }
      var += __shfl_xor(var, 1, 64); var += __shfl_xor(var, 2, 64);
      var += __shfl_xor(var, 4, 64); var += __shfl_xor(var, 8, 64);
      float rs = rsqrtf(var * (1.f / 128.f) + 1e-5f);
      if (rok) {
#pragma unroll
        for (int tt = 0; tt < 8; tt++) {
          int col = tt * 16 + lo;
          Cout[(size_t)row * 128 + col] = v[tt] * rs * lng[col] + lnb[col];
        }
      }
    }
  }
}

// ---------------- attention scalars ----------------

__global__ __launch_bounds__(256) void k_att_b(const u16* __restrict__ xhb,
                                               const float* __restrict__ attS,
                                               const float* __restrict__ attD,
                                               float* __restrict__ asrc,
                                               float* __restrict__ adst) {
  int w = threadIdx.x >> 6, lane = threadIdx.x & 63;
  int n = blockIdx.x * 4 + w;
  if (n >= NN) return;
  u32 xp = ((const u32*)xhb)[(size_t)n * 64 + lane];
  float x0 = __uint_as_float(xp << 16);
  float x1 = __uint_as_float(xp & 0xffff0000u);
  float2 as = *(const float2*)(attS + 2 * lane);
  float2 ad = *(const float2*)(attD + 2 * lane);
  float s = x0 * as.x + x1 * as.y;
  float d = x0 * ad.x + x1 * ad.y;
  s += __shfl_xor(s, 1, 64); s += __shfl_xor(s, 2, 64); s += __shfl_xor(s, 4, 64);
  d += __shfl_xor(d, 1, 64); d += __shfl_xor(d, 2, 64); d += __shfl_xor(d, 4, 64);
  if ((lane & 7) == 0) {
    int h = lane >> 3;
    asrc[n * HH + h] = s;
    adst[n * HH + h] = d;
  }
}

__global__ __launch_bounds__(256) void k_att_f(const float* __restrict__ xh,
                                               const float* __restrict__ attS,
                                               const float* __restrict__ attD,
                                               float* __restrict__ asrc,
                                               float* __restrict__ adst) {
  int w = threadIdx.x >> 6, lane = threadIdx.x & 63;
  int n = blockIdx.x * 4 + w;
  if (n >= NN) return;
  float v0 = xh[(size_t)n * 128 + lane];
  float v1 = xh[(size_t)n * 128 + 64 + lane];
  float s0 = v0 * attS[lane], s1 = v1 * attS[64 + lane];
  float d0 = v0 * attD[lane], d1 = v1 * attD[64 + lane];
#pragma unroll
  for (int m = 1; m < 16; m <<= 1) {
    s0 += __shfl_xor(s0, m, 64); s1 += __shfl_xor(s1, m, 64);
    d0 += __shfl_xor(d0, m, 64); d1 += __shfl_xor(d1, m, 64);
  }
  if ((lane & 15) == 0) {
    int h = lane >> 4;
    asrc[n * HH + h] = s0; asrc[n * HH + 4 + h] = s1;
    adst[n * HH + h] = d0; adst[n * HH + 4 + h] = d1;
  }
}

// ---------------- chunked edge-parallel: m, lg for CSR window [base, base+qn) ----------------
// one wave per position; lane covers cols (2l,2l+1), head h = l>>3.

__global__ __launch_bounds__(256) void k_edge_c(
    const int* __restrict__ ei, const int* __restrict__ perm,
    const float* __restrict__ eattr, const float* __restrict__ wle,
    const float* __restrict__ wag, const u16* __restrict__ xhb,
    const float* __restrict__ asrc, int base, int qn,
    u16* __restrict__ mC, float* __restrict__ lgC) {
  int lane = threadIdx.x & 63;
  int wid = (blockIdx.x * blockDim.x + threadIdx.x) >> 6;
  int nw = (gridDim.x * blockDim.x) >> 6;
  int h = lane >> 3;
  float wlA[16], wlB[16], wa[16];
#pragma unroll
  for (int k = 0; k < 16; k++) {
    float2 tv = *(const float2*)(wle + k * 128 + 2 * lane);
    wlA[k] = tv.x; wlB[k] = tv.y;
    wa[k] = wag[k * 8 + h];
  }
  for (int q = wid; q < qn; q += nw) {
    int e = perm[base + q];
    int src = ei[e];
    const float4* eap = (const float4*)(eattr + (size_t)e * EDD);
    float4 a0 = eap[0], a1 = eap[1], a2 = eap[2], a3 = eap[3];
    u32 xp = ((const u32*)xhb)[(size_t)src * 64 + lane];
    float ea[16] = {a0.x, a0.y, a0.z, a0.w, a1.x, a1.y, a1.z, a1.w,
                    a2.x, a2.y, a2.z, a2.w, a3.x, a3.y, a3.z, a3.w};
    float evA = 0.f, evB = 0.f, pe = 0.f;
#pragma unroll
    for (int k = 0; k < 16; k++) {
      evA += ea[k] * wlA[k];
      evB += ea[k] * wlB[k];
      pe += ea[k] * wa[k];
    }
    float x0 = __uint_as_float(xp << 16);
    float x1 = __uint_as_float(xp & 0xffff0000u);
    u32 mpk = (u32)f2bf(x0 * evA) | ((u32)f2bf(x1 * evB) << 16);
    ((u32*)mC)[(size_t)q * 64 + lane] = mpk;
    if ((lane & 7) == 0) lgC[(size_t)q * 8 + h] = asrc[src * HH + h] + pe;
  }
}

// ---------------- chunked aggregation: accumulate partials, finalize + LN1 ----------------
// finalize (softmax divide + bias + residual + LN1) happens in the chunk holding
// the node's LAST edge; partial sums RMW accv/ssumv (sequential chunks -> no race).

__global__ __launch_bounds__(256, 4) void k_aggc(
    const u16* __restrict__ mC, const float* __restrict__ lgC,
    const float* __restrict__ adst, const float* __restrict__ x,
    const float* __restrict__ cbias, const float* __restrict__ ln1g,
    const float* __restrict__ ln1b, const int* __restrict__ off,
    float* __restrict__ accv, float* __restrict__ ssumv,
    int base, int bEnd, float* __restrict__ hbuf) {
  int w = threadIdx.x >> 6, lane = threadIdx.x & 63;
  int n = blockIdx.x * 4 + w;
  if (n >= NN) return;
  int st = off[n], en = off[n + 1];
  int deg = en - st;
  int lo = st > base ? st : base;
  int hi = en < bEnd ? en : bEnd;
  int anchor = (deg > 0) ? (en - 1) : st;
  if (anchor > EE - 1) anchor = EE - 1;
  bool fin = (anchor >= base) && (anchor < bEnd);
  if (lo >= hi && !fin) return;
  int h = lane >> 3;
  float ad = adst[n * HH + h];
  float accA = 0.f, accB = 0.f, ss = 0.f;
  int cnt = hi - lo;
  if (cnt > 0) {
    const u32* mp = (const u32*)mC + (size_t)(lo - base) * 64 + lane;
    const float* lp = lgC + (size_t)(lo - base) * 8 + h;
    u32 m_c = mp[0];
    float lg_c = lp[0];
    for (int q = 0; q < cnt; ++q) {
      u32 m_n = 0; float lg_n = 0.f;
      if (q + 1 < cnt) { m_n = mp[(size_t)(q + 1) * 64]; lg_n = lp[(size_t)(q + 1) * 8]; }
      float al = lg_c + ad;
      al = (al >= 0.f) ? al : 0.2f * al;
      float ex = __expf(al);
      ss += ex;
      accA += ex * __uint_as_float(m_c << 16);
      accB += ex * __uint_as_float(m_c & 0xffff0000u);
      m_c = m_n; lg_c = lg_n;
    }
  }
  if (st < base) {  // prior-chunk partials exist
    float2 pa = *(const float2*)(accv + (size_t)n * 128 + 2 * lane);
    accA += pa.x; accB += pa.y;
    ss += ssumv[n * HH + h];
  }
  if (!fin) {
    *(float2*)(accv + (size_t)n * 128 + 2 * lane) = make_float2(accA, accB);
    if ((lane & 7) == 0) ssumv[n * HH + h] = ss;
    return;
  }
  float inv = 1.f / (ss + 1e-16f);
  float2 cb = *(const float2*)(cbias + 2 * lane);
  float2 xv = *(const float2*)(x + (size_t)n * 128 + 2 * lane);
  float v0 = xv.x + accA * inv + cb.x;
  float v1 = xv.y + accB * inv + cb.y;
  float sum = v0 + v1;
#pragma unroll
  for (int m = 1; m < 64; m <<= 1) sum += __shfl_xor(sum, m, 64);
  float mu = sum * (1.f / 128.f);
  float q0 = v0 - mu, q1 = v1 - mu;
  float vs = q0 * q0 + q1 * q1;
#pragma unroll
  for (int m = 1; m < 64; m <<= 1) vs += __shfl_xor(vs, m, 64);
  float rs = rsqrtf(vs * (1.f / 128.f) + 1e-5f);
  float2 g = *(const float2*)(ln1g + 2 * lane);
  float2 b = *(const float2*)(ln1b + 2 * lane);
  float2 o;
  o.x = q0 * rs * g.x + b.x;
  o.y = q1 * rs * g.y + b.y;
  *(float2*)(hbuf + (size_t)n * 128 + 2 * lane) = o;
}

// ---------------- LITE fallback (round-5): direct serial agg ----------------

__global__ __launch_bounds__(256, 4) void k_agg_lite(
    const int* __restrict__ ei, const float* __restrict__ eattr,
    const int* __restrict__ perm, const float* __restrict__ wle,
    const float* __restrict__ wag, const float* __restrict__ x,
    const float* __restrict__ xh, const float* __restrict__ asrc,
    const float* __restrict__ adst, const float* __restrict__ cbias,
    const float* __restrict__ ln1g, const float* __restrict__ ln1b,
    const int* __restrict__ off, float* __restrict__ hbuf) {
  int w = threadIdx.x >> 6, lane = threadIdx.x & 63;
  int n = blockIdx.x * 4 + w;
  if (n >= NN) return;
  int h = lane >> 3;
  float wlA[16], wlB[16], wa[16];
#pragma unroll
  for (int k = 0; k < 16; k++) {
    float2 tv = *(const float2*)(wle + k * 128 + 2 * lane);
    wlA[k] = tv.x; wlB[k] = tv.y;
    wa[k] = wag[k * 8 + h];
  }
  float ad = adst[n * HH + h];
  int st = off[n], cnt = off[n + 1] - st;
  float accA = 0.f, accB = 0.f, ssum = 0.f;
#define SRCQ(q) ((q) < cnt ? ei[perm[st + (q)]] : 0)
#define ROWQ(q) ((q) < cnt ? perm[st + (q)] : 0)
  int s0 = SRCQ(0), s1 = SRCQ(1);
  int r0 = ROWQ(0);
  const float4* p0 = (const float4*)(eattr + (size_t)r0 * EDD);
  float4 a0 = p0[0], a1 = p0[1], a2 = p0[2], a3 = p0[3];
  float2 xf0 = *(const float2*)(xh + (size_t)s0 * 128 + 2 * lane);
  float as0 = asrc[s0 * HH + h];
  float2 xf1 = *(const float2*)(xh + (size_t)s1 * 128 + 2 * lane);
  float as1 = asrc[s1 * HH + h];
  for (int q = 0; q < cnt; ++q) {
    int r1 = ROWQ(q + 1);
    const float4* pn = (const float4*)(eattr + (size_t)r1 * EDD);
    float4 b0 = pn[0], b1 = pn[1], b2 = pn[2], b3 = pn[3];
    int s2 = SRCQ(q + 2);
    float2 xf2 = *(const float2*)(xh + (size_t)s2 * 128 + 2 * lane);
    float as2 = asrc[s2 * HH + h];
    float ea[16] = {a0.x, a0.y, a0.z, a0.w, a1.x, a1.y, a1.z, a1.w,
                    a2.x, a2.y, a2.z, a2.w, a3.x, a3.y, a3.z, a3.w};
    float evA = 0.f, evB = 0.f, pe = 0.f;
#pragma unroll
    for (int k = 0; k < 16; k++) {
      evA += ea[k] * wlA[k];
      evB += ea[k] * wlB[k];
      pe += ea[k] * wa[k];
    }
    float al = as0 + ad + pe;
    al = (al >= 0.f) ? al : 0.2f * al;
    float ex = __expf(al);
    ssum += ex;
    accA += ex * xf0.x * evA;
    accB += ex * xf0.y * evB;
    a0 = b0; a1 = b1; a2 = b2; a3 = b3;
    xf0 = xf1; as0 = as1;
    xf1 = xf2; as1 = as2;
  }
#undef SRCQ
#undef ROWQ
  float inv = 1.f / (ssum + 1e-16f);
  float2 cb = *(const float2*)(cbias + 2 * lane);
  float2 xv = *(const float2*)(x + (size_t)n * 128 + 2 * lane);
  float v0 = xv.x + accA * inv + cb.x;
  float v1 = xv.y + accB * inv + cb.y;
  float sum = v0 + v1;
#pragma unroll
  for (int m = 1; m < 64; m <<= 1) sum += __shfl_xor(sum, m, 64);
  float mu = sum * (1.f / 128.f);
  float q0 = v0 - mu, q1 = v1 - mu;
  float vs = q0 * q0 + q1 * q1;
#pragma unroll
  for (int m = 1; m < 64; m <<= 1) vs += __shfl_xor(vs, m, 64);
  float rs = rsqrtf(vs * (1.f / 128.f) + 1e-5f);
  float2 g = *(const float2*)(ln1g + 2 * lane);
  float2 b = *(const float2*)(ln1b + 2 * lane);
  float2 o;
  o.x = q0 * rs * g.x + b.x;
  o.y = q1 * rs * g.y + b.y;
  *(float2*)(hbuf + (size_t)n * 128 + 2 * lane) = o;
}

// ---------------- launcher ----------------

// FULL (chunked) fixed layout — acc doubles as hbuf (finalize is in-place)
#define WQ_ACC 0ull              // N*128 f32 = 51,200,000
#define WQ_SSUM 51200000ull      // N*8  f32 =  3,200,000
#define WQ_XHB 54400000ull       // N*128 bf16 = 25,600,000
#define WQ_ASRC 80000000ull
#define WQ_ADST 83200000ull
#define WQ_OFF 86400000ull
#define WQ_CUR 86800128ull
#define WQ_PERM 87200256ull
#define WQ_BTG 93600256ull
#define WQ_WAG 93698560ull
#define WQ_CHUNK 93702656ull     // mC (Q*256 B) then lgC (Q*32 B)
// LITE layout
#define WL_XH 0ull
#define WL_HBUF 51200000ull
#define WL_ASRC 102400000ull
#define WL_ADST 105600000ull
#define WL_OFF 108800000ull
#define WL_CUR 109200128ull
#define WL_PERM 109600128ull
#define WL_WAG 116000128ull
#define WL_BTG 116000640ull

extern "C" void kernel_launch(void* const* d_in, const int* in_sizes, int n_in,
                              void* d_out, int out_size, void* d_ws, size_t ws_size,
                              hipStream_t stream) {
  const float* x     = (const float*)d_in[0];
  const int*   ei    = (const int*)d_in[1];
  const float* eattr = (const float*)d_in[2];
  const float* linW  = (const float*)d_in[3];
  const float* attS  = (const float*)d_in[4];
  const float* attD  = (const float*)d_in[5];
  const float* wle   = (const float*)d_in[6];
  const float* attE  = (const float*)d_in[7];
  const float* cbias = (const float*)d_in[8];
  const float* ln1g  = (const float*)d_in[9];
  const float* ln1b  = (const float*)d_in[10];
  const float* W1    = (const float*)d_in[11];
  const float* mb1   = (const float*)d_in[12];
  const float* W2    = (const float*)d_in[13];
  const float* mb2   = (const float*)d_in[14];
  const float* ln2g  = (const float*)d_in[15];
  const float* ln2b  = (const float*)d_in[16];

  char* ws = (char*)d_ws;
  float* outp = (float*)d_out;

  // runtime chunk size from available workspace
  long long availQ = ((long long)ws_size - (long long)WQ_CHUNK) / 288;
  int Q = (availQ > EE) ? EE : (int)availQ;
  bool full = (Q >= 100000);

  if (full) {
    float* accv = (float*)(ws + WQ_ACC);   // partials, then h (in-place)
    float* ssumv= (float*)(ws + WQ_SSUM);
    u16*   xhb  = (u16*)(ws + WQ_XHB);
    float* asrc = (float*)(ws + WQ_ASRC);
    float* adst = (float*)(ws + WQ_ADST);
    int*   off  = (int*)(ws + WQ_OFF);
    int*   cur  = (int*)(ws + WQ_CUR);
    int*   perm = (int*)(ws + WQ_PERM);
    u16*   Btg  = (u16*)(ws + WQ_BTG);
    float* WAg  = (float*)(ws + WQ_WAG);
    u16*   mC   = (u16*)(ws + WQ_CHUNK);
    float* lgC  = (float*)(ws + WQ_CHUNK + (size_t)Q * 256);
    int*   loc  = (int*)(ws + WQ_ACC);    // scan scratch (free pre-agg)
    int*   bsum = (int*)(ws + WQ_SSUM);

    int nchunk = (EE + Q - 1) / Q;

    hipMemsetAsync(cur, 0, NN * sizeof(int), stream);
    k_hist<<<4096, 256, 0, stream>>>(ei, cur);
    k_scan_a<<<NBLK, 1024, 0, stream>>>(cur, loc, bsum);
    k_scan_b<<<1, 64, 0, stream>>>(bsum, off);
    k_scan_c<<<NBLK, 1024, 0, stream>>>(loc, bsum, off, cur);
    k_scatter<<<4096, 256, 0, stream>>>(ei, cur, perm);
    k_prep<<<25, 256, 0, stream>>>(linW, W1, W2, wle, attE, Btg, WAg);
    // xhb = bf16(x @ lin_W)
    k_gemm<3><<<(NN + 63) / 64, 256, 0, stream>>>(x, Btg, x, x, x, x, (float*)xhb);
    k_att_b<<<(NN + 3) / 4, 256, 0, stream>>>(xhb, attS, attD, asrc, adst);
    for (int c = 0; c < nchunk; ++c) {
      int base = c * Q;
      int qn = (EE - base < Q) ? (EE - base) : Q;
      k_edge_c<<<2048, 256, 0, stream>>>(ei, perm, eattr, wle, WAg, xhb, asrc,
                                         base, qn, mC, lgC);
      k_aggc<<<(NN + 3) / 4, 256, 0, stream>>>(mC, lgC, adst, x, cbias, ln1g,
                                               ln1b, off, accv, ssumv,
                                               base, base + qn, accv);
    }
    // G = gelu(h @ W1 + b1) -> outp (scratch), then out = LN2(h + G @ W2 + b2)
    k_gemm<1><<<(NN + 63) / 64, 256, 0, stream>>>(accv, Btg + 16384, mb1, accv,
                                                  ln2g, ln2b, outp);
    k_gemm<2><<<(NN + 63) / 64, 256, 0, stream>>>(outp, Btg + 32768, mb2, accv,
                                                  ln2g, ln2b, outp);
  } else {
    float* xh   = (float*)(ws + WL_XH);
    float* hbuf = (float*)(ws + WL_HBUF);
    float* asrc = (float*)(ws + WL_ASRC);
    float* adst = (float*)(ws + WL_ADST);
    int*   off  = (int*)(ws + WL_OFF);
    int*   cur  = (int*)(ws + WL_CUR);
    int*   perm = (int*)(ws + WL_PERM);
    float* WAg  = (float*)(ws + WL_WAG);
    u16*   Btg  = (u16*)(ws + WL_BTG);
    int*   loc  = (int*)(ws + WL_XH);
    int*   bsum = (int*)(ws + WL_ADST);

    hipMemsetAsync(cur, 0, NN * sizeof(int), stream);
    k_hist<<<4096, 256, 0, stream>>>(ei, cur);
    k_scan_a<<<NBLK, 1024, 0, stream>>>(cur, loc, bsum);
    k_scan_b<<<1, 64, 0, stream>>>(bsum, off);
    k_scan_c<<<NBLK, 1024, 0, stream>>>(loc, bsum, off, cur);
    k_scatter<<<4096, 256, 0, stream>>>(ei, cur, perm);
    k_prep<<<25, 256, 0, stream>>>(linW, W1, W2, wle, attE, Btg, WAg);
    k_gemm<0><<<(NN + 63) / 64, 256, 0, stream>>>(x, Btg, x, x, x, x, xh);
    k_att_f<<<(NN + 3) / 4, 256, 0, stream>>>(xh, attS, attD, asrc, adst);
    k_agg_lite<<<(NN + 3) / 4, 256, 0, stream>>>(ei, eattr, perm, wle, WAg, x, xh,
                                                 asrc, adst, cbias, ln1g, ln1b,
                                                 off, hbuf);
    k_gemm<1><<<(NN + 63) / 64, 256, 0, stream>>>(hbuf, Btg + 16384, mb1, hbuf,
                                                  ln2g, ln2b, xh);
    k_gemm<2><<<(NN + 63) / 64, 256, 0, stream>>>(xh, Btg + 32768, mb2, hbuf,
                                                  ln2g, ln2b, outp);
  }
}

// Round 8
// 893.106 us; speedup vs baseline: 1.5702x; 1.5702x over previous
//
#include <hip/hip_runtime.h>
#include <hip/hip_bf16.h>
#include <math.h>

#define NN 100000
#define EE 1600000
#define DD 128
#define HH 8
#define CC 16
#define EDD 16
#define NBLK 98  // ceil(NN/1024)

typedef unsigned short u16;
typedef unsigned int u32;
typedef __attribute__((ext_vector_type(8))) short short8;
typedef __attribute__((ext_vector_type(4))) float f32x4;

__device__ __forceinline__ u16 f2bf(float f) {
  u32 u = __float_as_uint(f);
  u32 r = u + 0x7fff + ((u >> 16) & 1);
  return (u16)(r >> 16);
}

// ---------------- CSR build ----------------

__global__ void k_hist(const int* __restrict__ ei, int* __restrict__ cnt) {
  int stride = gridDim.x * blockDim.x;
  for (int e = blockIdx.x * blockDim.x + threadIdx.x; e < EE; e += stride)
    atomicAdd(&cnt[ei[EE + e]], 1);
}

__global__ __launch_bounds__(1024) void k_scan_a(const int* __restrict__ cnt,
                                                 int* __restrict__ loc,
                                                 int* __restrict__ bsum) {
  __shared__ int wpart[16];
  int t = threadIdx.x, lane = t & 63, w = t >> 6;
  int i = blockIdx.x * 1024 + t;
  int v = (i < NN) ? cnt[i] : 0;
  int x = v;
#pragma unroll
  for (int d = 1; d < 64; d <<= 1) {
    int y = __shfl_up(x, d, 64);
    if (lane >= d) x += y;
  }
  if (lane == 63) wpart[w] = x;
  __syncthreads();
  if (w == 0) {
    int p = (lane < 16) ? wpart[lane] : 0;
#pragma unroll
    for (int d = 1; d < 16; d <<= 1) {
      int y = __shfl_up(p, d, 64);
      if (lane >= d) p += y;
    }
    if (lane < 16) wpart[lane] = p;
  }
  __syncthreads();
  int excl = ((w > 0) ? wpart[w - 1] : 0) + (x - v);
  if (i < NN) loc[i] = excl;
  if (t == 0) bsum[blockIdx.x] = wpart[15];
}

__global__ void k_scan_b(int* __restrict__ bsum, int* __restrict__ off) {
  if (blockIdx.x == 0 && threadIdx.x == 0) {
    int run = 0;
    for (int b = 0; b < NBLK; b++) { int s = bsum[b]; bsum[b] = run; run += s; }
    off[NN] = run;
  }
}

__global__ __launch_bounds__(1024) void k_scan_c(const int* __restrict__ loc,
                                                 const int* __restrict__ bsum,
                                                 int* __restrict__ off,
                                                 int* __restrict__ cur) {
  int i = blockIdx.x * 1024 + threadIdx.x;
  if (i < NN) {
    int v = loc[i] + bsum[i >> 10];
    off[i] = v;
    cur[i] = v;
  }
}

// ---------------- prep: bf16-transposed weights + WA ----------------

__global__ void k_prep(const float* __restrict__ linW, const float* __restrict__ W1,
                       const float* __restrict__ W2, const float* __restrict__ wle,
                       const float* __restrict__ attE, u16* __restrict__ Btg,
                       float* __restrict__ WAg) {
  int tid = blockIdx.x * 256 + threadIdx.x;
  if (tid < 6144) {
    int m = tid >> 11;
    int cid = tid & 2047;
    const float* W = (m == 0) ? linW : (m == 1) ? W1 : W2;
    int n = cid >> 4, kc = cid & 15;
    union { u16 us[8]; uint4 q4; } P;
#pragma unroll
    for (int j = 0; j < 8; j++) P.us[j] = f2bf(W[(kc * 8 + j) * 128 + n]);
    ((uint4*)(Btg + (size_t)m * 16384))[cid] = P.q4;
  } else if (tid < 6272) {
    int i = tid - 6144;
    int k = i >> 3, h = i & 7;
    float s = 0.f;
#pragma unroll
    for (int c = 0; c < 16; c++) s += wle[k * 128 + h * 16 + c] * attE[h * 16 + c];
    WAg[k * 8 + h] = s;
  }
}

// ---------------- bf16 MFMA GEMM: [N x 128] @ [128 x 128] ----------------
// EPI: 0 = f32 store, 1 = bias+gelu, 2 = bias+residual+LN2, 3 = bf16 store

template <int EPI>
__global__ __launch_bounds__(256) void k_gemm(
    const float* __restrict__ A, const u16* __restrict__ Bt,
    const float* __restrict__ bias, const float* __restrict__ resid,
    const float* __restrict__ lng, const float* __restrict__ lnb,
    float* __restrict__ Cout) {
  __shared__ u16 As[64 * 136];
  __shared__ u16 Bs[128 * 136];
  int t = threadIdx.x;
  int row0 = blockIdx.x * 64;
#pragma unroll
  for (int i = 0; i < 8; i++) {
    int cid = t + 256 * i;
    int n = cid >> 4, kc = cid & 15;
    uint4 v = ((const uint4*)Bt)[cid];
    *((uint4*)(&Bs[n * 136 + kc * 8])) = v;
  }
  {
    int r = t >> 2, q = t & 3;
    const float* Ar = A + (size_t)(row0 + r) * 128 + q * 32;
    bool ok = (row0 + r) < NN;
#pragma unroll
    for (int j = 0; j < 4; j++) {
      float4 u = ok ? ((const float4*)Ar)[2 * j] : make_float4(0.f, 0.f, 0.f, 0.f);
      float4 v = ok ? ((const float4*)Ar)[2 * j + 1] : make_float4(0.f, 0.f, 0.f, 0.f);
      union { u16 us[8]; uint4 q4; } P;
      P.us[0] = f2bf(u.x); P.us[1] = f2bf(u.y); P.us[2] = f2bf(u.z); P.us[3] = f2bf(u.w);
      P.us[4] = f2bf(v.x); P.us[5] = f2bf(v.y); P.us[6] = f2bf(v.z); P.us[7] = f2bf(v.w);
      *((uint4*)(&As[r * 136 + (q * 4 + j) * 8])) = P.q4;
    }
  }
  __syncthreads();
  int w = t >> 6, lane = t & 63, lo = lane & 15, hi = lane >> 4;
  f32x4 acc[8];
  f32x4 zero = {0.f, 0.f, 0.f, 0.f};
#pragma unroll
  for (int i = 0; i < 8; i++) acc[i] = zero;
  const u16* ApL = &As[(w * 16 + lo) * 136];
  const u16* BpL = &Bs[lo * 136];
#pragma unroll
  for (int ks = 0; ks < 4; ks++) {
    short8 af = *((const short8*)(ApL + ks * 32 + hi * 8));
#pragma unroll
    for (int tt = 0; tt < 8; tt++) {
      short8 bf = *((const short8*)(BpL + tt * 16 * 136 + ks * 32 + hi * 8));
      acc[tt] = __builtin_amdgcn_mfma_f32_16x16x32_bf16(af, bf, acc[tt], 0, 0, 0);
    }
  }
  if (EPI == 0) {
#pragma unroll
    for (int j = 0; j < 4; j++) {
      int row = row0 + w * 16 + hi * 4 + j;
      if (row < NN) {
#pragma unroll
        for (int tt = 0; tt < 8; tt++)
          Cout[(size_t)row * 128 + tt * 16 + lo] = acc[tt][j];
      }
    }
  } else if (EPI == 3) {
    u16* Cb = (u16*)Cout;
#pragma unroll
    for (int j = 0; j < 4; j++) {
      int row = row0 + w * 16 + hi * 4 + j;
      if (row < NN) {
#pragma unroll
        for (int tt = 0; tt < 8; tt++)
          Cb[(size_t)row * 128 + tt * 16 + lo] = f2bf(acc[tt][j]);
      }
    }
  } else if (EPI == 1) {
#pragma unroll
    for (int j = 0; j < 4; j++) {
      int row = row0 + w * 16 + hi * 4 + j;
      if (row < NN) {
#pragma unroll
        for (int tt = 0; tt < 8; tt++) {
          int col = tt * 16 + lo;
          float z = acc[tt][j] + bias[col];
          float g = 0.5f * z * (1.f + erff(z * 0.70710678118654752f));
          Cout[(size_t)row * 128 + col] = g;
        }
      }
    }
  } else {
#pragma unroll
    for (int j = 0; j < 4; j++) {
      int row = row0 + w * 16 + hi * 4 + j;
      bool rok = row < NN;
      float v[8];
      float sum = 0.f;
#pragma unroll
      for (int tt = 0; tt < 8; tt++) {
        int col = tt * 16 + lo;
        float hv = rok ? resid[(size_t)row * 128 + col] : 0.f;
        v[tt] = hv + acc[tt][j] + bias[col];
        sum += v[tt];
      }
      sum += __shfl_xor(sum, 1, 64); sum += __shfl_xor(sum, 2, 64);
      sum += __shfl_xor(sum, 4, 64); sum += __shfl_xor(sum, 8, 64);
      float mu = sum * (1.f / 128.f);
      float var = 0.f;
#pragma unroll
      for (int tt = 0; tt < 8; tt++) { v[tt] -= mu; var += v[tt] * v[tt]; }
      var += __shfl_xor(var, 1, 64); var += __shfl_xor(var, 2, 64);
      var += __shfl_xor(var, 4, 64); var += __shfl_xor(var, 8, 64);
      float rs = rsqrtf(var * (1.f / 128.f) + 1e-5f);
      if (rok) {
#pragma unroll
        for (int tt = 0; tt < 8; tt++) {
          int col = tt * 16 + lo;
          Cout[(size_t)row * 128 + col] = v[tt] * rs * lng[col] + lnb[col];
        }
      }
    }
  }
}

// ---------------- attention scalars ----------------

__global__ __launch_bounds__(256) void k_att_b(const u16* __restrict__ xhb,
                                               const float* __restrict__ attS,
                                               const float* __restrict__ attD,
                                               float* __restrict__ asrc,
                                               float* __restrict__ adst) {
  int w = threadIdx.x >> 6, lane = threadIdx.x & 63;
  int n = blockIdx.x * 4 + w;
  if (n >= NN) return;
  u32 xp = ((const u32*)xhb)[(size_t)n * 64 + lane];
  float x0 = __uint_as_float(xp << 16);
  float x1 = __uint_as_float(xp & 0xffff0000u);
  float2 as = *(const float2*)(attS + 2 * lane);
  float2 ad = *(const float2*)(attD + 2 * lane);
  float s = x0 * as.x + x1 * as.y;
  float d = x0 * ad.x + x1 * ad.y;
  s += __shfl_xor(s, 1, 64); s += __shfl_xor(s, 2, 64); s += __shfl_xor(s, 4, 64);
  d += __shfl_xor(d, 1, 64); d += __shfl_xor(d, 2, 64); d += __shfl_xor(d, 4, 64);
  if ((lane & 7) == 0) {
    int h = lane >> 3;
    asrc[n * HH + h] = s;
    adst[n * HH + h] = d;
  }
}

__global__ __launch_bounds__(256) void k_att_f(const float* __restrict__ xh,
                                               const float* __restrict__ attS,
                                               const float* __restrict__ attD,
                                               float* __restrict__ asrc,
                                               float* __restrict__ adst) {
  int w = threadIdx.x >> 6, lane = threadIdx.x & 63;
  int n = blockIdx.x * 4 + w;
  if (n >= NN) return;
  float v0 = xh[(size_t)n * 128 + lane];
  float v1 = xh[(size_t)n * 128 + 64 + lane];
  float s0 = v0 * attS[lane], s1 = v1 * attS[64 + lane];
  float d0 = v0 * attD[lane], d1 = v1 * attD[64 + lane];
#pragma unroll
  for (int m = 1; m < 16; m <<= 1) {
    s0 += __shfl_xor(s0, m, 64); s1 += __shfl_xor(s1, m, 64);
    d0 += __shfl_xor(d0, m, 64); d1 += __shfl_xor(d1, m, 64);
  }
  if ((lane & 15) == 0) {
    int h = lane >> 4;
    asrc[n * HH + h] = s0; asrc[n * HH + 4 + h] = s1;
    adst[n * HH + h] = d0; adst[n * HH + 4 + h] = d1;
  }
}

// ---------------- fused scatter + edge precompute ----------------
// thread per (edge, head); edges in ORIGINAL order (coalesced eattr read).
// h==0 lane claims the CSR slot p via atomicAdd; broadcast to the 8-lane group.
// writes: eatb[p] (bf16 eattr row), exP[p][h] = exp(leaky(logit)), srcP[p].

__global__ __launch_bounds__(256) void k_scatEP(
    const int* __restrict__ ei, const float* __restrict__ eattr,
    const float* __restrict__ wag, const float* __restrict__ asrc,
    const float* __restrict__ adst, int* __restrict__ cur,
    u16* __restrict__ eatb, float* __restrict__ exP, int* __restrict__ srcP) {
  __shared__ float swa[128];
  if (threadIdx.x < 128) swa[threadIdx.x] = wag[threadIdx.x];
  __syncthreads();
  int tt = blockIdx.x * 256 + threadIdx.x;  // exact: 50000*256 == EE*8
  int e = tt >> 3, h = tt & 7;
  int lane = threadIdx.x & 63;
  int src = ei[e];
  int dst = ei[EE + e];
  const float4* eap = (const float4*)(eattr + (size_t)e * EDD);
  float4 a0 = eap[0], a1 = eap[1], a2 = eap[2], a3 = eap[3];
  float ea[16] = {a0.x, a0.y, a0.z, a0.w, a1.x, a1.y, a1.z, a1.w,
                  a2.x, a2.y, a2.z, a2.w, a3.x, a3.y, a3.z, a3.w};
  float pe = 0.f;
#pragma unroll
  for (int k = 0; k < 16; k++) pe += ea[k] * swa[k * 8 + h];
  int p = 0;
  if (h == 0) p = atomicAdd(&cur[dst], 1);
  p = __shfl(p, lane & ~7, 64);
  float al = asrc[src * 8 + h] + adst[dst * 8 + h] + pe;
  al = (al >= 0.f) ? al : 0.2f * al;
  exP[(size_t)p * 8 + h] = __expf(al);
  if (h == 0) srcP[p] = src;
  if (h < 2) {
    union { u16 us[8]; uint4 q4; } P;
#pragma unroll
    for (int j = 0; j < 8; j++) P.us[j] = f2bf(ea[h * 8 + j]);
    ((uint4*)eatb)[(size_t)p * 2 + h] = P.q4;
  }
}

// ---------------- lean aggregation + LN1 (2 waves per dst node) ----------------
// all streams sequential; only xhb gather is indirect (L2-resident, 25.6 MB).

__global__ __launch_bounds__(256) void k_agg3(
    const u16* __restrict__ eatb, const float* __restrict__ exP,
    const int* __restrict__ srcP, const u16* __restrict__ xhb,
    const float* __restrict__ x, const float* __restrict__ cbias,
    const float* __restrict__ ln1g, const float* __restrict__ ln1b,
    const float* __restrict__ wle, const int* __restrict__ off,
    float* __restrict__ hbuf) {
  __shared__ float lacc[2][2][128];
  __shared__ float lss[2][2][8];
  int t = threadIdx.x;
  int lane = t & 63;
  int w01 = (t >> 6) & 1;
  int nn = t >> 7;
  int n = blockIdx.x * 2 + nn;   // NN even, grid*2 == NN: no guard needed
  int h = lane >> 3;
  float wlA[16], wlB[16];
#pragma unroll
  for (int k = 0; k < 16; k++) {
    float2 tv = *(const float2*)(wle + k * 128 + 2 * lane);
    wlA[k] = tv.x; wlB[k] = tv.y;
  }
  int st = off[n], en = off[n + 1];
  int mid = st + ((en - st + 1) >> 1);
  int lo = w01 ? mid : st;
  int hi = w01 ? en : mid;
  int cnt = hi - lo;
  float accA = 0.f, accB = 0.f, ss = 0.f;
  if (cnt > 0) {
    const uint4* ep = (const uint4*)eatb + (size_t)lo * 2;
    const float* xp_ = exP + (size_t)lo * 8 + h;
    const int* sp = srcP + lo;
    const u32* xhx = (const u32*)xhb;
    int cm1 = cnt - 1;
#define CL(i) ((i) < cm1 ? (i) : cm1)
    int s1 = sp[CL(1)];
    uint4 ea0 = ep[0], ea1 = ep[1];
    float ex0 = xp_[0];
    int s0 = sp[0];
    u32 xw0 = xhx[(size_t)s0 * 64 + lane];
    for (int q = 0; q < cnt; ++q) {
      int s2 = sp[CL(q + 2)];
      u32 xw1 = xhx[(size_t)s1 * 64 + lane];
      int qn = CL(q + 1);
      uint4 eb0 = ep[(size_t)qn * 2], eb1 = ep[(size_t)qn * 2 + 1];
      float exn = xp_[(size_t)qn * 8];
      u32 uu[8] = {ea0.x, ea0.y, ea0.z, ea0.w, ea1.x, ea1.y, ea1.z, ea1.w};
      float evA = 0.f, evB = 0.f;
#pragma unroll
      for (int k2 = 0; k2 < 8; k2++) {
        float elo = __uint_as_float(uu[k2] << 16);
        float ehi = __uint_as_float(uu[k2] & 0xffff0000u);
        evA = fmaf(elo, wlA[2 * k2], evA);
        evA = fmaf(ehi, wlA[2 * k2 + 1], evA);
        evB = fmaf(elo, wlB[2 * k2], evB);
        evB = fmaf(ehi, wlB[2 * k2 + 1], evB);
      }
      float x0 = __uint_as_float(xw0 << 16);
      float x1 = __uint_as_float(xw0 & 0xffff0000u);
      ss += ex0;
      float eA = ex0 * evA, eB = ex0 * evB;
      accA = fmaf(eA, x0, accA);
      accB = fmaf(eB, x1, accB);
      ea0 = eb0; ea1 = eb1; ex0 = exn; xw0 = xw1; s1 = s2;
    }
#undef CL
  }
  lacc[nn][w01][lane] = accA;
  lacc[nn][w01][64 + lane] = accB;
  if ((lane & 7) == 0) lss[nn][w01][h] = ss;
  __syncthreads();
  if (w01 == 0) {
    accA += lacc[nn][1][lane];
    accB += lacc[nn][1][64 + lane];
    ss += lss[nn][1][h];
    float inv = 1.f / (ss + 1e-16f);
    float2 cb = *(const float2*)(cbias + 2 * lane);
    float2 xv = *(const float2*)(x + (size_t)n * 128 + 2 * lane);
    float v0 = xv.x + accA * inv + cb.x;
    float v1 = xv.y + accB * inv + cb.y;
    float sum = v0 + v1;
#pragma unroll
    for (int m = 1; m < 64; m <<= 1) sum += __shfl_xor(sum, m, 64);
    float mu = sum * (1.f / 128.f);
    float q0 = v0 - mu, q1 = v1 - mu;
    float vs = q0 * q0 + q1 * q1;
#pragma unroll
    for (int m = 1; m < 64; m <<= 1) vs += __shfl_xor(vs, m, 64);
    float rs = rsqrtf(vs * (1.f / 128.f) + 1e-5f);
    float2 g = *(const float2*)(ln1g + 2 * lane);
    float2 b = *(const float2*)(ln1b + 2 * lane);
    float2 o;
    o.x = q0 * rs * g.x + b.x;
    o.y = q1 * rs * g.y + b.y;
    *(float2*)(hbuf + (size_t)n * 128 + 2 * lane) = o;
  }
}

// ---------------- LITE fallback: direct serial agg (R4) ----------------

__global__ void k_scatter(const int* __restrict__ ei, int* __restrict__ cur,
                          int* __restrict__ perm) {
  int stride = gridDim.x * blockDim.x;
  for (int e = blockIdx.x * blockDim.x + threadIdx.x; e < EE; e += stride) {
    int d = ei[EE + e];
    int p = atomicAdd(&cur[d], 1);
    perm[p] = e;
  }
}

__global__ __launch_bounds__(256, 4) void k_agg_lite(
    const int* __restrict__ ei, const float* __restrict__ eattr,
    const int* __restrict__ perm, const float* __restrict__ wle,
    const float* __restrict__ wag, const float* __restrict__ x,
    const float* __restrict__ xh, const float* __restrict__ asrc,
    const float* __restrict__ adst, const float* __restrict__ cbias,
    const float* __restrict__ ln1g, const float* __restrict__ ln1b,
    const int* __restrict__ off, float* __restrict__ hbuf) {
  int w = threadIdx.x >> 6, lane = threadIdx.x & 63;
  int n = blockIdx.x * 4 + w;
  if (n >= NN) return;
  int h = lane >> 3;
  float wlA[16], wlB[16], wa[16];
#pragma unroll
  for (int k = 0; k < 16; k++) {
    float2 tv = *(const float2*)(wle + k * 128 + 2 * lane);
    wlA[k] = tv.x; wlB[k] = tv.y;
    wa[k] = wag[k * 8 + h];
  }
  float ad = adst[n * HH + h];
  int st = off[n], cnt = off[n + 1] - st;
  float accA = 0.f, accB = 0.f, ssum = 0.f;
#define SRCQ(q) ((q) < cnt ? ei[perm[st + (q)]] : 0)
#define ROWQ(q) ((q) < cnt ? perm[st + (q)] : 0)
  int s0 = SRCQ(0), s1 = SRCQ(1);
  int r0 = ROWQ(0);
  const float4* p0 = (const float4*)(eattr + (size_t)r0 * EDD);
  float4 a0 = p0[0], a1 = p0[1], a2 = p0[2], a3 = p0[3];
  float2 xf0 = *(const float2*)(xh + (size_t)s0 * 128 + 2 * lane);
  float as0 = asrc[s0 * HH + h];
  float2 xf1 = *(const float2*)(xh + (size_t)s1 * 128 + 2 * lane);
  float as1 = asrc[s1 * HH + h];
  for (int q = 0; q < cnt; ++q) {
    int r1 = ROWQ(q + 1);
    const float4* pn = (const float4*)(eattr + (size_t)r1 * EDD);
    float4 b0 = pn[0], b1 = pn[1], b2 = pn[2], b3 = pn[3];
    int s2 = SRCQ(q + 2);
    float2 xf2 = *(const float2*)(xh + (size_t)s2 * 128 + 2 * lane);
    float as2 = asrc[s2 * HH + h];
    float ea[16] = {a0.x, a0.y, a0.z, a0.w, a1.x, a1.y, a1.z, a1.w,
                    a2.x, a2.y, a2.z, a2.w, a3.x, a3.y, a3.z, a3.w};
    float evA = 0.f, evB = 0.f, pe = 0.f;
#pragma unroll
    for (int k = 0; k < 16; k++) {
      evA += ea[k] * wlA[k];
      evB += ea[k] * wlB[k];
      pe += ea[k] * wa[k];
    }
    float al = as0 + ad + pe;
    al = (al >= 0.f) ? al : 0.2f * al;
    float ex = __expf(al);
    ssum += ex;
    accA += ex * xf0.x * evA;
    accB += ex * xf0.y * evB;
    a0 = b0; a1 = b1; a2 = b2; a3 = b3;
    xf0 = xf1; as0 = as1;
    xf1 = xf2; as1 = as2;
  }
#undef SRCQ
#undef ROWQ
  float inv = 1.f / (ssum + 1e-16f);
  float2 cb = *(const float2*)(cbias + 2 * lane);
  float2 xv = *(const float2*)(x + (size_t)n * 128 + 2 * lane);
  float v0 = xv.x + accA * inv + cb.x;
  float v1 = xv.y + accB * inv + cb.y;
  float sum = v0 + v1;
#pragma unroll
  for (int m = 1; m < 64; m <<= 1) sum += __shfl_xor(sum, m, 64);
  float mu = sum * (1.f / 128.f);
  float q0 = v0 - mu, q1 = v1 - mu;
  float vs = q0 * q0 + q1 * q1;
#pragma unroll
  for (int m = 1; m < 64; m <<= 1) vs += __shfl_xor(vs, m, 64);
  float rs = rsqrtf(vs * (1.f / 128.f) + 1e-5f);
  float2 g = *(const float2*)(ln1g + 2 * lane);
  float2 b = *(const float2*)(ln1b + 2 * lane);
  float2 o;
  o.x = q0 * rs * g.x + b.x;
  o.y = q1 * rs * g.y + b.y;
  *(float2*)(hbuf + (size_t)n * 128 + 2 * lane) = o;
}

// ---------------- launcher ----------------

// FULL v3 layout (192.9 MB; proven ws >= 224.9 MB)
#define WQ_ACC 0ull              // N*128 f32 (acc -> hbuf in place; scan loc scratch)
#define WQ_XHB 51200000ull       // N*128 bf16 (bsum scratch pre-gemm)
#define WQ_ASRC 76800000ull
#define WQ_ADST 80000000ull
#define WQ_OFF 83200000ull
#define WQ_CUR 83600128ull
#define WQ_BTG 84000256ull
#define WQ_WAG 84098560ull
#define WQ_EATB 84102656ull      // E*16 bf16 = 51,200,000
#define WQ_SRCP 135302656ull     // E int
#define WQ_EXP 141702656ull      // E*8 f32 = 51,200,000
#define WQ_NEED 192902656ull
// LITE layout
#define WL_XH 0ull
#define WL_HBUF 51200000ull
#define WL_ASRC 102400000ull
#define WL_ADST 105600000ull
#define WL_OFF 108800000ull
#define WL_CUR 109200128ull
#define WL_PERM 109600128ull
#define WL_WAG 116000128ull
#define WL_BTG 116000640ull

extern "C" void kernel_launch(void* const* d_in, const int* in_sizes, int n_in,
                              void* d_out, int out_size, void* d_ws, size_t ws_size,
                              hipStream_t stream) {
  const float* x     = (const float*)d_in[0];
  const int*   ei    = (const int*)d_in[1];
  const float* eattr = (const float*)d_in[2];
  const float* linW  = (const float*)d_in[3];
  const float* attS  = (const float*)d_in[4];
  const float* attD  = (const float*)d_in[5];
  const float* wle   = (const float*)d_in[6];
  const float* attE  = (const float*)d_in[7];
  const float* cbias = (const float*)d_in[8];
  const float* ln1g  = (const float*)d_in[9];
  const float* ln1b  = (const float*)d_in[10];
  const float* W1    = (const float*)d_in[11];
  const float* mb1   = (const float*)d_in[12];
  const float* W2    = (const float*)d_in[13];
  const float* mb2   = (const float*)d_in[14];
  const float* ln2g  = (const float*)d_in[15];
  const float* ln2b  = (const float*)d_in[16];

  char* ws = (char*)d_ws;
  float* outp = (float*)d_out;
  bool full = ws_size >= WQ_NEED;

  if (full) {
    float* accv = (float*)(ws + WQ_ACC);
    u16*   xhb  = (u16*)(ws + WQ_XHB);
    float* asrc = (float*)(ws + WQ_ASRC);
    float* adst = (float*)(ws + WQ_ADST);
    int*   off  = (int*)(ws + WQ_OFF);
    int*   cur  = (int*)(ws + WQ_CUR);
    u16*   Btg  = (u16*)(ws + WQ_BTG);
    float* WAg  = (float*)(ws + WQ_WAG);
    u16*   eatb = (u16*)(ws + WQ_EATB);
    int*   srcP = (int*)(ws + WQ_SRCP);
    float* exP  = (float*)(ws + WQ_EXP);
    int*   loc  = (int*)(ws + WQ_ACC);   // scratch pre-agg
    int*   bsum = (int*)(ws + WQ_XHB);   // scratch pre-gemm<3>

    hipMemsetAsync(cur, 0, NN * sizeof(int), stream);
    k_hist<<<4096, 256, 0, stream>>>(ei, cur);
    k_scan_a<<<NBLK, 1024, 0, stream>>>(cur, loc, bsum);
    k_scan_b<<<1, 64, 0, stream>>>(bsum, off);
    k_scan_c<<<NBLK, 1024, 0, stream>>>(loc, bsum, off, cur);
    k_prep<<<25, 256, 0, stream>>>(linW, W1, W2, wle, attE, Btg, WAg);
    k_gemm<3><<<(NN + 63) / 64, 256, 0, stream>>>(x, Btg, x, x, x, x, (float*)xhb);
    k_att_b<<<(NN + 3) / 4, 256, 0, stream>>>(xhb, attS, attD, asrc, adst);
    k_scatEP<<<50000, 256, 0, stream>>>(ei, eattr, WAg, asrc, adst, cur,
                                        eatb, exP, srcP);
    k_agg3<<<NN / 2, 256, 0, stream>>>(eatb, exP, srcP, xhb, x, cbias,
                                       ln1g, ln1b, wle, off, accv);
    k_gemm<1><<<(NN + 63) / 64, 256, 0, stream>>>(accv, Btg + 16384, mb1, accv,
                                                  ln2g, ln2b, outp);
    k_gemm<2><<<(NN + 63) / 64, 256, 0, stream>>>(outp, Btg + 32768, mb2, accv,
                                                  ln2g, ln2b, outp);
  } else {
    float* xh   = (float*)(ws + WL_XH);
    float* hbuf = (float*)(ws + WL_HBUF);
    float* asrc = (float*)(ws + WL_ASRC);
    float* adst = (float*)(ws + WL_ADST);
    int*   off  = (int*)(ws + WL_OFF);
    int*   cur  = (int*)(ws + WL_CUR);
    int*   perm = (int*)(ws + WL_PERM);
    float* WAg  = (float*)(ws + WL_WAG);
    u16*   Btg  = (u16*)(ws + WL_BTG);
    int*   loc  = (int*)(ws + WL_XH);
    int*   bsum = (int*)(ws + WL_ADST);

    hipMemsetAsync(cur, 0, NN * sizeof(int), stream);
    k_hist<<<4096, 256, 0, stream>>>(ei, cur);
    k_scan_a<<<NBLK, 1024, 0, stream>>>(cur, loc, bsum);
    k_scan_b<<<1, 64, 0, stream>>>(bsum, off);
    k_scan_c<<<NBLK, 1024, 0, stream>>>(loc, bsum, off, cur);
    k_scatter<<<4096, 256, 0, stream>>>(ei, cur, perm);
    k_prep<<<25, 256, 0, stream>>>(linW, W1, W2, wle, attE, Btg, WAg);
    k_gemm<0><<<(NN + 63) / 64, 256, 0, stream>>>(x, Btg, x, x, x, x, xh);
    k_att_f<<<(NN + 3) / 4, 256, 0, stream>>>(xh, attS, attD, asrc, adst);
    k_agg_lite<<<(NN + 3) / 4, 256, 0, stream>>>(ei, eattr, perm, wle, WAg, x, xh,
                                                 asrc, adst, cbias, ln1g, ln1b,
                                                 off, hbuf);
    k_gemm<1><<<(NN + 63) / 64, 256, 0, stream>>>(hbuf, Btg + 16384, mb1, hbuf,
                                                  ln2g, ln2b, xh);
    k_gemm<2><<<(NN + 63) / 64, 256, 0, stream>>>(xh, Btg + 32768, mb2, hbuf,
                                                  ln2g, ln2b, outp);
  }
}